// Round 2
// baseline (316.990 us; speedup 1.0000x reference)
//
#include <hip/hip_runtime.h>
#include <hip/hip_cooperative_groups.h>
#include <math.h>

#define B 128
#define T 1024
#define H 256
#define L 16
#define INV_TEMP (1.0f/0.07f)
#define NEG_INF -1e30f
#define GRID_FUSED 512   // 2 blocks/CU guaranteed by __launch_bounds__(256,2)

namespace cg = cooperative_groups;

// ws layout (only seg<nseg regions are ever written/read -> no memset):
//   ws_pp   : float[B][4][L][H]   per-seg prototype partial sums   8 MB
//   ws_cntp : int[B][4][L]        per-seg label counts             32 KB

// ---------------------------------------------------------------------------
// Fused cooperative kernel: phase 1 = prototype partial sums (1024 units over
// 512 blocks), grid.sync(), phase 2 = dots + log-softmax + masked mean
// (512 units, 1 per block). Single dispatch -> launch gap gone, and the
// kernel's cost is directly visible in rocprof.
__global__ __launch_bounds__(256, 2) void fused_kernel(
    const float* __restrict__ feat, const int* __restrict__ dlen,
    const int* __restrict__ labels, float* __restrict__ ws_pp,
    int* __restrict__ ws_cntp, float* __restrict__ out) {
  __shared__ float acc[4][L * 128];   // 32 KB; phase 2 reuses first 16 KB as pr
  __shared__ int labs[256];
  __shared__ int cnts[L];
  __shared__ float red[256];

  const int tid = threadIdx.x;
  if (blockIdx.x == 0 && tid == 0) out[0] = 0.f;   // ordered by grid.sync()

  // ------------------------------ phase 1: proto partial sums
  for (int u = blockIdx.x; u < B * 8; u += GRID_FUSED) {
    const int b = u >> 3;
    const int chunk = (u >> 2) & 1;
    const int seg = u & 3;
    const int len = dlen[b];                // block-uniform
    if (seg * 256 >= len) continue;         // uniform: safe with syncthreads

    const int w = tid >> 6;
    const int lane = tid & 63;

    for (int i = tid; i < 4 * L * 128; i += 256) ((float*)acc)[i] = 0.f;
    labs[tid] = labels[(size_t)b * T + seg * 256 + tid];
    if (tid < L) cnts[tid] = 0;
    __syncthreads();

    if (chunk == 0 && (seg * 256 + tid) < len) atomicAdd(&cnts[labs[tid]], 1);

    int nt = len - seg * 256 - w * 64;      // tokens this wave processes
    if (nt > 64) nt = 64;
    const float2* fbase = (const float2*)(feat +
        ((size_t)b * T + seg * 256 + w * 64) * H + chunk * 128);
    float* a = acc[w];

    int j = 0;
    for (; j + 4 <= nt; j += 4) {
      float2 f0 = fbase[(size_t)(j + 0) * (H / 2) + lane];
      float2 f1 = fbase[(size_t)(j + 1) * (H / 2) + lane];
      float2 f2 = fbase[(size_t)(j + 2) * (H / 2) + lane];
      float2 f3 = fbase[(size_t)(j + 3) * (H / 2) + lane];
      const int l0 = labs[w * 64 + j + 0];
      const int l1 = labs[w * 64 + j + 1];
      const int l2 = labs[w * 64 + j + 2];
      const int l3 = labs[w * 64 + j + 3];
      float2* p0 = (float2*)&a[l0 * 128 + lane * 2];
      { float2 v = *p0; v.x += f0.x; v.y += f0.y; *p0 = v; }
      float2* p1 = (float2*)&a[l1 * 128 + lane * 2];
      { float2 v = *p1; v.x += f1.x; v.y += f1.y; *p1 = v; }
      float2* p2 = (float2*)&a[l2 * 128 + lane * 2];
      { float2 v = *p2; v.x += f2.x; v.y += f2.y; *p2 = v; }
      float2* p3 = (float2*)&a[l3 * 128 + lane * 2];
      { float2 v = *p3; v.x += f3.x; v.y += f3.y; *p3 = v; }
    }
    for (; j < nt; ++j) {
      float2 f = fbase[(size_t)j * (H / 2) + lane];
      const int lab = labs[w * 64 + j];
      float2* p = (float2*)&a[lab * 128 + lane * 2];
      float2 v = *p; v.x += f.x; v.y += f.y; *p = v;
    }
    __syncthreads();

    float* op = ws_pp + (((size_t)b * 4 + seg) * L) * H + chunk * 128;
    for (int e = tid; e < L * 128; e += 256) {
      const float s = acc[0][e] + acc[1][e] + acc[2][e] + acc[3][e];
      op[(e >> 7) * H + (e & 127)] = s;
    }
    if (chunk == 0 && tid < L) ws_cntp[(b * 4 + seg) * L + tid] = cnts[tid];
    __syncthreads();   // protect acc/labs/cnts reuse by next unit
  }

  cg::this_grid().sync();

  // ------------------------------ phase 2: dots + log-softmax + masked mean
  float* pr = &acc[0][0];   // 16 KB prototype stage (reuses acc storage)
  for (int u = blockIdx.x; u < B * 4; u += GRID_FUSED) {
    const int b = u >> 2;
    const int seg = u & 3;
    const int len = dlen[b];
    if (seg * 256 >= len) continue;        // contributes exactly 0 (uniform)
    const int nseg = (len + 255) >> 8;     // 1..4 valid segments

    if (tid < L) {
      const int* cp = ws_cntp + b * 4 * L + tid;
      int c = 0;
      for (int s = 0; s < nseg; ++s) c += cp[s * L];
      cnts[tid] = c;
    }
    __syncthreads();

    const float* gp = ws_pp + (size_t)b * 4 * L * H;
    for (int i = tid; i < L * H; i += 256) {
      const int l = i >> 8;                // H = 256
      float s = 0.f;
      for (int sg = 0; sg < nseg; ++sg)
        s += gp[(sg * L + l) * H + (i & (H - 1))];
      const int cn = cnts[l];
      pr[i] = s * (cn > 0 ? 1.f / (float)cn : 0.f);
    }
    __syncthreads();

    const int t = seg * 256 + tid;
    float tok = 0.f;

    if (t < len) {
      const float4* f4 = (const float4*)(feat + ((size_t)b * T + t) * H);
      float dot[L];
#pragma unroll
      for (int l = 0; l < L; ++l) dot[l] = 0.f;

#pragma unroll 4
      for (int cb = 0; cb < 16; ++cb) {    // 16-float chunks of the token row
        float4 f[4];
#pragma unroll
        for (int q = 0; q < 4; ++q) f[q] = f4[cb * 4 + q];
#pragma unroll
        for (int q = 0; q < 4; ++q) {
#pragma unroll
          for (int l = 0; l < L; ++l) {
            const float4 p = *(const float4*)&pr[l * H + cb * 16 + q * 4];
            dot[l] += f[q].x * p.x + f[q].y * p.y +
                      f[q].z * p.z + f[q].w * p.w;
          }
        }
      }

      float lg[L];
#pragma unroll
      for (int l = 0; l < L; ++l)
        lg[l] = (cnts[l] > 0) ? dot[l] * INV_TEMP : NEG_INF;
      float m = lg[0];
#pragma unroll
      for (int l = 1; l < L; ++l) m = fmaxf(m, lg[l]);
      float se = 0.f;
#pragma unroll
      for (int l = 0; l < L; ++l) se += expf(lg[l] - m);
      const float lsp = m + logf(se);

      const int lab = labels[(size_t)b * T + t];
      float pos = 0.f;
#pragma unroll
      for (int l = 0; l < L; ++l) pos += (l == lab) ? lg[l] : 0.f;

      tok = lsp - pos;
    }

    red[tid] = tok;
    __syncthreads();
#pragma unroll
    for (int s = 128; s > 0; s >>= 1) {
      if (tid < s) red[tid] += red[tid + s];
      __syncthreads();
    }
    if (tid == 0) atomicAdd(out, red[0] / ((float)len * (float)B));
    __syncthreads();   // protect cnts/pr/red reuse by next unit
  }
}

// ---------------------------------------------------------------------------
// Fallback path (identical to round-1 two-kernel version) in case cooperative
// launch is rejected under graph capture.
__global__ __launch_bounds__(256) void proto_kernel(
    const float* __restrict__ feat, const int* __restrict__ dlen,
    const int* __restrict__ labels, float* __restrict__ ws_pp,
    int* __restrict__ ws_cntp, float* __restrict__ out) {
  __shared__ float acc[4][L * 128];
  __shared__ int labs[256];
  __shared__ int cnt[L];

  const int bx = blockIdx.x;
  if (bx == 0 && threadIdx.x == 0) out[0] = 0.f;

  const int b = bx >> 3;
  const int chunk = (bx >> 2) & 1;
  const int seg = bx & 3;
  const int tid = threadIdx.x;
  const int w = tid >> 6;
  const int lane = tid & 63;

  const int len = dlen[b];
  if (seg * 256 >= len) return;

  for (int i = tid; i < 4 * L * 128; i += 256) ((float*)acc)[i] = 0.f;
  labs[tid] = labels[(size_t)b * T + seg * 256 + tid];
  if (tid < L) cnt[tid] = 0;
  __syncthreads();

  if (chunk == 0 && (seg * 256 + tid) < len) atomicAdd(&cnt[labs[tid]], 1);

  int nt = len - seg * 256 - w * 64;
  if (nt > 64) nt = 64;
  const float2* fbase = (const float2*)(feat +
      ((size_t)b * T + seg * 256 + w * 64) * H + chunk * 128);
  float* a = acc[w];

  int j = 0;
  for (; j + 4 <= nt; j += 4) {
    float2 f0 = fbase[(size_t)(j + 0) * (H / 2) + lane];
    float2 f1 = fbase[(size_t)(j + 1) * (H / 2) + lane];
    float2 f2 = fbase[(size_t)(j + 2) * (H / 2) + lane];
    float2 f3 = fbase[(size_t)(j + 3) * (H / 2) + lane];
    const int l0 = labs[w * 64 + j + 0];
    const int l1 = labs[w * 64 + j + 1];
    const int l2 = labs[w * 64 + j + 2];
    const int l3 = labs[w * 64 + j + 3];
    float2* p0 = (float2*)&a[l0 * 128 + lane * 2];
    { float2 v = *p0; v.x += f0.x; v.y += f0.y; *p0 = v; }
    float2* p1 = (float2*)&a[l1 * 128 + lane * 2];
    { float2 v = *p1; v.x += f1.x; v.y += f1.y; *p1 = v; }
    float2* p2 = (float2*)&a[l2 * 128 + lane * 2];
    { float2 v = *p2; v.x += f2.x; v.y += f2.y; *p2 = v; }
    float2* p3 = (float2*)&a[l3 * 128 + lane * 2];
    { float2 v = *p3; v.x += f3.x; v.y += f3.y; *p3 = v; }
  }
  for (; j < nt; ++j) {
    float2 f = fbase[(size_t)j * (H / 2) + lane];
    const int lab = labs[w * 64 + j];
    float2* p = (float2*)&a[lab * 128 + lane * 2];
    float2 v = *p; v.x += f.x; v.y += f.y; *p = v;
  }
  __syncthreads();

  float* op = ws_pp + (((size_t)b * 4 + seg) * L) * H + chunk * 128;
  for (int e = tid; e < L * 128; e += 256) {
    const float s = acc[0][e] + acc[1][e] + acc[2][e] + acc[3][e];
    op[(e >> 7) * H + (e & 127)] = s;
  }
  if (chunk == 0 && tid < L) ws_cntp[(b * 4 + seg) * L + tid] = cnt[tid];
}

__global__ __launch_bounds__(256) void dotsloss_kernel(
    const float* __restrict__ feat, const int* __restrict__ dlen,
    const int* __restrict__ labels, const float* __restrict__ ws_pp,
    const int* __restrict__ ws_cntp, float* __restrict__ out) {
  __shared__ float pr[L * H];
  __shared__ int cnts[L];
  __shared__ float red[256];

  const int b = blockIdx.x >> 2;
  const int seg = blockIdx.x & 3;
  const int tid = threadIdx.x;

  const int len = dlen[b];
  if (seg * 256 >= len) return;
  const int nseg = (len + 255) >> 8;

  if (tid < L) {
    const int* cp = ws_cntp + b * 4 * L + tid;
    int c = 0;
    for (int s = 0; s < nseg; ++s) c += cp[s * L];
    cnts[tid] = c;
  }
  __syncthreads();

  const float* gp = ws_pp + (size_t)b * 4 * L * H;
  for (int i = tid; i < L * H; i += 256) {
    const int l = i >> 8;
    float s = 0.f;
    for (int sg = 0; sg < nseg; ++sg) s += gp[(sg * L + l) * H + (i & (H - 1))];
    const int cn = cnts[l];
    pr[i] = s * (cn > 0 ? 1.f / (float)cn : 0.f);
  }
  __syncthreads();

  const int t = seg * 256 + tid;
  float tok = 0.f;

  if (t < len) {
    const float4* f4 = (const float4*)(feat + ((size_t)b * T + t) * H);
    float dot[L];
#pragma unroll
    for (int l = 0; l < L; ++l) dot[l] = 0.f;

#pragma unroll 4
    for (int cb = 0; cb < 16; ++cb) {
      float4 f[4];
#pragma unroll
      for (int q = 0; q < 4; ++q) f[q] = f4[cb * 4 + q];
#pragma unroll
      for (int q = 0; q < 4; ++q) {
#pragma unroll
        for (int l = 0; l < L; ++l) {
          const float4 p = *(const float4*)&pr[l * H + cb * 16 + q * 4];
          dot[l] += f[q].x * p.x + f[q].y * p.y +
                    f[q].z * p.z + f[q].w * p.w;
        }
      }
    }

    float lg[L];
#pragma unroll
    for (int l = 0; l < L; ++l)
      lg[l] = (cnts[l] > 0) ? dot[l] * INV_TEMP : NEG_INF;
    float m = lg[0];
#pragma unroll
    for (int l = 1; l < L; ++l) m = fmaxf(m, lg[l]);
    float se = 0.f;
#pragma unroll
    for (int l = 0; l < L; ++l) se += expf(lg[l] - m);
    const float lsp = m + logf(se);

    const int lab = labels[(size_t)b * T + t];
    float pos = 0.f;
#pragma unroll
    for (int l = 0; l < L; ++l) pos += (l == lab) ? lg[l] : 0.f;

    tok = lsp - pos;
  }

  red[tid] = tok;
  __syncthreads();
#pragma unroll
  for (int s = 128; s > 0; s >>= 1) {
    if (tid < s) red[tid] += red[tid + s];
    __syncthreads();
  }
  if (tid == 0) atomicAdd(out, red[0] / ((float)len * (float)B));
}

extern "C" void kernel_launch(void* const* d_in, const int* in_sizes, int n_in,
                              void* d_out, int out_size, void* d_ws, size_t ws_size,
                              hipStream_t stream) {
  const float* feat = (const float*)d_in[0];
  const int* dlen = (const int*)d_in[1];
  const int* labels = (const int*)d_in[2];
  float* out = (float*)d_out;

  float* ws_pp = (float*)d_ws;                           // B*4*L*H floats
  int* ws_cntp = (int*)(ws_pp + (size_t)B * 4 * L * H);  // B*4*L ints

  void* args[] = {(void*)&feat, (void*)&dlen, (void*)&labels,
                  (void*)&ws_pp, (void*)&ws_cntp, (void*)&out};
  hipError_t err = hipLaunchCooperativeKernel(
      fused_kernel, dim3(GRID_FUSED), dim3(256), args, 0, stream);
  if (err != hipSuccess) {
    // graph-capture or runtime rejected cooperative launch: two-kernel path
    proto_kernel<<<B * 8, 256, 0, stream>>>(feat, dlen, labels, ws_pp,
                                            ws_cntp, out);
    dotsloss_kernel<<<B * 4, 256, 0, stream>>>(feat, dlen, labels, ws_pp,
                                               ws_cntp, out);
  }
}

// Round 3
// 239.714 us; speedup vs baseline: 1.3224x; 1.3224x over previous
//
#include <hip/hip_runtime.h>
#include <math.h>

#define B 128
#define T 1024
#define H 256
#define L 16
#define INV_TEMP (1.0f/0.07f)
#define NEG_INF -1e30f

// ws layout (only seg<nseg regions are ever written/read -> no memset):
//   ws_pp   : float[B][4][L][H]   per-seg prototype partial sums   8 MB
//   ws_cntp : int[B][4][L]        per-seg label counts             32 KB

// ---------------------------------------------------------------------------
// Kernel 1: prototype partial sums. grid = B * 2 chunks * 4 segs = 1024 blocks
// (4 blocks/CU, 16 waves/CU). Block owns a disjoint [b][seg][L][chunk*128..)
// slice -> plain stores, no atomics. Invalid segments exit immediately.
// Block 0 zeroes the output scalar (replaces the memset dispatch).
__global__ __launch_bounds__(256) void proto_kernel(
    const float* __restrict__ feat, const int* __restrict__ dlen,
    const int* __restrict__ labels, float* __restrict__ ws_pp,
    int* __restrict__ ws_cntp, float* __restrict__ out) {
  __shared__ float acc[4][L * 128];   // 32 KB, wave-private slabs
  __shared__ int labs[256];
  __shared__ int cnt[L];

  const int bx = blockIdx.x;
  if (bx == 0 && threadIdx.x == 0) out[0] = 0.f;

  const int b = bx >> 3;
  const int chunk = (bx >> 2) & 1;
  const int seg = bx & 3;
  const int tid = threadIdx.x;
  const int w = tid >> 6;
  const int lane = tid & 63;

  const int len = dlen[b];
  if (seg * 256 >= len) return;   // fully invalid segment: nothing published

  for (int i = tid; i < 4 * L * 128 / 4; i += 256)
    ((float4*)acc)[i] = make_float4(0.f, 0.f, 0.f, 0.f);
  labs[tid] = labels[(size_t)b * T + seg * 256 + tid];
  if (tid < L) cnt[tid] = 0;
  __syncthreads();

  if (chunk == 0 && (seg * 256 + tid) < len) atomicAdd(&cnt[labs[tid]], 1);

  int nt = len - seg * 256 - w * 64;   // tokens this wave processes
  if (nt > 64) nt = 64;
  const float2* fbase = (const float2*)(feat +
      ((size_t)b * T + seg * 256 + w * 64) * H + chunk * 128);
  float* a = acc[w];

  int j = 0;
  for (; j + 4 <= nt; j += 4) {
    float2 f0 = fbase[(size_t)(j + 0) * (H / 2) + lane];
    float2 f1 = fbase[(size_t)(j + 1) * (H / 2) + lane];
    float2 f2 = fbase[(size_t)(j + 2) * (H / 2) + lane];
    float2 f3 = fbase[(size_t)(j + 3) * (H / 2) + lane];
    const int l0 = labs[w * 64 + j + 0];
    const int l1 = labs[w * 64 + j + 1];
    const int l2 = labs[w * 64 + j + 2];
    const int l3 = labs[w * 64 + j + 3];
    float2* p0 = (float2*)&a[l0 * 128 + lane * 2];
    { float2 v = *p0; v.x += f0.x; v.y += f0.y; *p0 = v; }
    float2* p1 = (float2*)&a[l1 * 128 + lane * 2];
    { float2 v = *p1; v.x += f1.x; v.y += f1.y; *p1 = v; }
    float2* p2 = (float2*)&a[l2 * 128 + lane * 2];
    { float2 v = *p2; v.x += f2.x; v.y += f2.y; *p2 = v; }
    float2* p3 = (float2*)&a[l3 * 128 + lane * 2];
    { float2 v = *p3; v.x += f3.x; v.y += f3.y; *p3 = v; }
  }
  for (; j < nt; ++j) {
    float2 f = fbase[(size_t)j * (H / 2) + lane];
    const int lab = labs[w * 64 + j];
    float2* p = (float2*)&a[lab * 128 + lane * 2];
    float2 v = *p; v.x += f.x; v.y += f.y; *p = v;
  }
  __syncthreads();

  float* op = ws_pp + (((size_t)b * 4 + seg) * L) * H + chunk * 128;
  for (int e = tid; e < L * 128 / 4; e += 256) {   // 512 float4
    const float4 s0 = ((const float4*)acc[0])[e];
    const float4 s1 = ((const float4*)acc[1])[e];
    const float4 s2 = ((const float4*)acc[2])[e];
    const float4 s3 = ((const float4*)acc[3])[e];
    float4 s;
    s.x = s0.x + s1.x + s2.x + s3.x;
    s.y = s0.y + s1.y + s2.y + s3.y;
    s.z = s0.z + s1.z + s2.z + s3.z;
    s.w = s0.w + s1.w + s2.w + s3.w;
    *(float4*)&op[(e >> 5) * H + ((e & 31) << 2)] = s;
  }
  if (chunk == 0 && tid < L) ws_cntp[(b * 4 + seg) * L + tid] = cnt[tid];
}

// ---------------------------------------------------------------------------
// Kernel 2 (dots+loss): grid = B*8 octant blocks of 128 threads, 1 token per
// thread, full H -> dot[L] in registers, log-softmax + masked mean fused.
// 16.6 KB LDS -> 8 blocks/CU co-resident = 16 waves/CU (2x round-1 TLP).
// Feature row walked in 64B chunks with explicit ping-pong prefetch (one
// chunk always in flight); launch_bounds(128,4) gives 128-VGPR headroom so
// the pipeline actually materializes (round-2 compile sat at 52 VGPR).
#define DOT_BODY(CB, FR)                                                   \
  _Pragma("unroll") for (int q = 0; q < 4; ++q) {                          \
    _Pragma("unroll") for (int l = 0; l < L; ++l) {                        \
      const float4 p = *(const float4*)&pr[l * H + (CB) * 16 + q * 4];     \
      dot[l] += FR[q].x * p.x + FR[q].y * p.y +                            \
                FR[q].z * p.z + FR[q].w * p.w;                             \
    }                                                                      \
  }

__global__ __launch_bounds__(128, 4) void dotsloss_kernel(
    const float* __restrict__ feat, const int* __restrict__ dlen,
    const int* __restrict__ labels, const float* __restrict__ ws_pp,
    const int* __restrict__ ws_cntp, float* __restrict__ out) {
  __shared__ float pr[L * H];   // 16 KB prototypes, full H
  __shared__ int cnts[L];
  __shared__ float red[128];

  const int b = blockIdx.x >> 3;
  const int oct = blockIdx.x & 7;      // 8 x 128-token octants
  const int tid = threadIdx.x;

  const int len = dlen[b];
  if (oct * 128 >= len) return;        // contributes exactly 0 (uniform)
  const int nseg = (len + 255) >> 8;   // 1..4 valid segments

  if (tid < L) {
    const int* cp = ws_cntp + b * 4 * L + tid;
    int c = 0;
    for (int s = 0; s < nseg; ++s) c += cp[s * L];
    cnts[tid] = c;
  }
  __syncthreads();

  // assemble prototypes: sum valid segment partials, divide by count (f4 vec)
  const float4* gp4 = (const float4*)(ws_pp + (size_t)b * 4 * L * H);
  for (int i = tid; i < L * H / 4; i += 128) {   // 1024 float4, 8 iters
    const int l = i >> 6;                        // 64 float4 per label row
    float4 s = gp4[i];                           // nseg >= 1 always
    for (int sg = 1; sg < nseg; ++sg) {
      const float4 t2 = gp4[sg * (L * 64) + i];
      s.x += t2.x; s.y += t2.y; s.z += t2.z; s.w += t2.w;
    }
    const int cn = cnts[l];
    const float inv = (cn > 0) ? 1.f / (float)cn : 0.f;
    ((float4*)pr)[i] = make_float4(s.x * inv, s.y * inv, s.z * inv, s.w * inv);
  }
  __syncthreads();

  const int t = oct * 128 + tid;
  float tok = 0.f;

  if (t < len) {
    const float4* f4 = (const float4*)(feat + ((size_t)b * T + t) * H);
    float dot[L];
#pragma unroll
    for (int l = 0; l < L; ++l) dot[l] = 0.f;

    float4 fa[4], fb[4];
#pragma unroll
    for (int q = 0; q < 4; ++q) fa[q] = f4[q];

    for (int cb = 0; cb < 14; cb += 2) {
#pragma unroll
      for (int q = 0; q < 4; ++q) fb[q] = f4[(cb + 1) * 4 + q];
      DOT_BODY(cb, fa);
#pragma unroll
      for (int q = 0; q < 4; ++q) fa[q] = f4[(cb + 2) * 4 + q];
      DOT_BODY(cb + 1, fb);
    }
#pragma unroll
    for (int q = 0; q < 4; ++q) fb[q] = f4[15 * 4 + q];
    DOT_BODY(14, fa);
    DOT_BODY(15, fb);

    float lg[L];
#pragma unroll
    for (int l = 0; l < L; ++l)
      lg[l] = (cnts[l] > 0) ? dot[l] * INV_TEMP : NEG_INF;
    float m = lg[0];
#pragma unroll
    for (int l = 1; l < L; ++l) m = fmaxf(m, lg[l]);
    float se = 0.f;
#pragma unroll
    for (int l = 0; l < L; ++l) se += expf(lg[l] - m);
    const float lsp = m + logf(se);

    const int lab = labels[(size_t)b * T + t];
    float pos = 0.f;
#pragma unroll
    for (int l = 0; l < L; ++l) pos += (l == lab) ? lg[l] : 0.f;

    tok = lsp - pos;
  }

  red[tid] = tok;
  __syncthreads();
#pragma unroll
  for (int s = 64; s > 0; s >>= 1) {
    if (tid < s) red[tid] += red[tid + s];
    __syncthreads();
  }
  if (tid == 0) atomicAdd(out, red[0] / ((float)len * (float)B));
}

extern "C" void kernel_launch(void* const* d_in, const int* in_sizes, int n_in,
                              void* d_out, int out_size, void* d_ws, size_t ws_size,
                              hipStream_t stream) {
  const float* feat = (const float*)d_in[0];
  const int* dlen = (const int*)d_in[1];
  const int* labels = (const int*)d_in[2];
  float* out = (float*)d_out;

  float* ws_pp = (float*)d_ws;                           // B*4*L*H floats
  int* ws_cntp = (int*)(ws_pp + (size_t)B * 4 * L * H);  // B*4*L ints

  proto_kernel<<<B * 8, 256, 0, stream>>>(feat, dlen, labels, ws_pp,
                                          ws_cntp, out);
  dotsloss_kernel<<<B * 8, 128, 0, stream>>>(feat, dlen, labels, ws_pp,
                                             ws_cntp, out);
}